// Round 1
// baseline (397.591 us; speedup 1.0000x reference)
//
#include <hip/hip_runtime.h>
#include <hip/hip_bf16.h>

typedef __bf16 bf16;
typedef __bf16 bf16x8 __attribute__((ext_vector_type(8)));
typedef __bf16 bf16x4 __attribute__((ext_vector_type(4)));
typedef float  f32x4  __attribute__((ext_vector_type(4)));
typedef float  f32x16 __attribute__((ext_vector_type(16)));

#define AS1 __attribute__((address_space(1)))
#define AS3 __attribute__((address_space(3)))

__device__ __forceinline__ void gload_lds16(const bf16* g, bf16* l) {
    __builtin_amdgcn_global_load_lds((const AS1 unsigned int*)g,
                                     (AS3 unsigned int*)l, 16, 0, 0);
}

// ------- cast fp32 -> bf16 (7 tensors) + mask bias, via grid.z -------
__global__ __launch_bounds__(256) void cast8_k(
    const float* __restrict__ s0, const float* __restrict__ s1,
    const float* __restrict__ s2, const float* __restrict__ s3,
    const float* __restrict__ s4, const float* __restrict__ s5,
    const float* __restrict__ s6,
    bf16* __restrict__ d0, bf16* __restrict__ d1, bf16* __restrict__ d2,
    bf16* __restrict__ d3, bf16* __restrict__ d4, bf16* __restrict__ d5,
    bf16* __restrict__ d6,
    const int* __restrict__ m, float* __restrict__ mb,
    int n_big, int n_small) {
    int z = blockIdx.z;
    int i = (blockIdx.x * 256 + threadIdx.x) * 8;
    if (z == 7) {  // mask -> exp2-domain additive bias
        if (i >= 4096) return;
        int4 a = *(const int4*)(m + i);
        int4 b = *(const int4*)(m + i + 4);
        float4 o0, o1;
        o0.x = (a.x == 0) ? -1.442695e9f : -17.3123405f;
        o0.y = (a.y == 0) ? -1.442695e9f : -17.3123405f;
        o0.z = (a.z == 0) ? -1.442695e9f : -17.3123405f;
        o0.w = (a.w == 0) ? -1.442695e9f : -17.3123405f;
        o1.x = (b.x == 0) ? -1.442695e9f : -17.3123405f;
        o1.y = (b.y == 0) ? -1.442695e9f : -17.3123405f;
        o1.z = (b.z == 0) ? -1.442695e9f : -17.3123405f;
        o1.w = (b.w == 0) ? -1.442695e9f : -17.3123405f;
        *(float4*)(mb + i) = o0;
        *(float4*)(mb + i + 4) = o1;
        return;
    }
    const float* s = (z == 0) ? s0 : (z == 1) ? s1 : (z == 2) ? s2
                   : (z == 3) ? s3 : (z == 4) ? s4 : (z == 5) ? s5 : s6;
    bf16* d = (z == 0) ? d0 : (z == 1) ? d1 : (z == 2) ? d2
            : (z == 3) ? d3 : (z == 4) ? d4 : (z == 5) ? d5 : d6;
    int n = (z < 3) ? n_big : n_small;
    if (i >= n) return;
    float4 a = *(const float4*)(s + i);
    float4 b = *(const float4*)(s + i + 4);
    bf16x8 o;
    o[0] = (bf16)a.x; o[1] = (bf16)a.y; o[2] = (bf16)a.z; o[3] = (bf16)a.w;
    o[4] = (bf16)b.x; o[5] = (bf16)b.y; o[6] = (bf16)b.z; o[7] = (bf16)b.w;
    *(bf16x8*)(d + i) = o;
}

// ---------------- BT-GEMM, 32x32x16 MFMA, 128x128 tile ----------------
// TRANS=true: compute C^T and store to VpT with the bit2<->bit3 key
// permutation baked in (for attn's PV A-frag trick).
template <typename OUT_T, bool TRANS>
__device__ __forceinline__ void gemm32_core(
    const bf16* __restrict__ A, const bf16* __restrict__ W,
    const float* __restrict__ bias, OUT_T* __restrict__ C,
    int M, int N, int K) {
    __shared__ bf16 Asm[128 * 64];
    __shared__ bf16 Bsm[128 * 64];
    const int lane = threadIdx.x & 63;
    const int w = threadIdx.x >> 6;
    const int l31 = lane & 31;
    const int h = lane >> 5;
    const int x7 = l31 & 7;
    const int m0 = blockIdx.x * 128;
    const int n0 = blockIdx.y * 128;
    const int srow = lane >> 3;
    const int scol = ((lane & 7) ^ srow) * 8;
    const int wm = (w & 1) * 64;
    const int wn = (w >> 1) * 64;

    f32x16 acc[2][2] = {};

    for (int k0 = 0; k0 < K; k0 += 64) {
#pragma unroll
        for (int c = 0; c < 4; ++c) {
            int r = w * 32 + c * 8;
            gload_lds16(A + (size_t)(m0 + r + srow) * K + k0 + scol, &Asm[r * 64]);
            gload_lds16(W + (size_t)(n0 + r + srow) * K + k0 + scol, &Bsm[r * 64]);
        }
        __syncthreads();
#pragma unroll
        for (int step = 0; step < 4; ++step) {
            bf16x8 af[2], bfv[2];
#pragma unroll
            for (int i = 0; i < 2; ++i)
                af[i] = *(const bf16x8*)&Asm[(wm + i * 32 + l31) * 64 +
                                             (((step * 2 + h) ^ x7) * 8)];
#pragma unroll
            for (int j = 0; j < 2; ++j)
                bfv[j] = *(const bf16x8*)&Bsm[(wn + j * 32 + l31) * 64 +
                                              (((step * 2 + h) ^ x7) * 8)];
#pragma unroll
            for (int i = 0; i < 2; ++i)
#pragma unroll
                for (int j = 0; j < 2; ++j)
                    acc[i][j] = TRANS
                        ? __builtin_amdgcn_mfma_f32_32x32x16_bf16(bfv[j], af[i],
                                                                  acc[i][j], 0, 0, 0)
                        : __builtin_amdgcn_mfma_f32_32x32x16_bf16(af[i], bfv[j],
                                                                  acc[i][j], 0, 0, 0);
        }
        __syncthreads();
    }
    if (!TRANS) {
#pragma unroll
        for (int i = 0; i < 2; ++i)
#pragma unroll
            for (int j = 0; j < 2; ++j) {
                int col = n0 + wn + j * 32 + l31;
                float bv = bias[col];
#pragma unroll
                for (int g = 0; g < 4; ++g)
#pragma unroll
                    for (int rr = 0; rr < 4; ++rr) {
                        int row = m0 + wm + i * 32 + rr + g * 8 + 4 * h;
                        C[(size_t)row * N + col] =
                            (OUT_T)(acc[i][j][g * 4 + rr] + bv);
                    }
            }
    } else {
#pragma unroll
        for (int i = 0; i < 2; ++i) {
            int s = m0 + wm + i * 32 + l31;
            int b = s >> 11;
            int sl = s & 2047;
            int sp = (sl & ~12) | ((sl & 4) << 1) | ((sl & 8) >> 1);
#pragma unroll
            for (int j = 0; j < 2; ++j)
#pragma unroll
                for (int g = 0; g < 4; ++g) {
                    float4 bv4 = *(const float4*)&bias[n0 + wn + j * 32 + g * 8 + 4 * h];
#pragma unroll
                    for (int rr = 0; rr < 4; ++rr) {
                        int n = n0 + wn + j * 32 + g * 8 + 4 * h + rr;
                        C[(size_t)(b * 1024 + n) * 2048 + sp] =
                            (OUT_T)(acc[i][j][g * 4 + rr] + (&bv4.x)[rr]);
                    }
                }
        }
    }
}

__global__ __launch_bounds__(256) void gemm_qkv(
    const bf16* __restrict__ qb, const bf16* __restrict__ kb, const bf16* __restrict__ vb,
    const bf16* __restrict__ Wq, const bf16* __restrict__ Wk, const bf16* __restrict__ Wv,
    const float* __restrict__ bq, const float* __restrict__ bk, const float* __restrict__ bv,
    bf16* __restrict__ Qp, bf16* __restrict__ Kp, bf16* __restrict__ VpT) {
    int z = blockIdx.z;
    if (z == 2) {
        gemm32_core<bf16, true>(vb, Wv, bv, VpT, 4096, 1024, 1024);
    } else {
        const bf16* A = (z == 0) ? qb : kb;
        const bf16* W = (z == 0) ? Wq : Wk;
        const float* bi = (z == 0) ? bq : bk;
        bf16* C = (z == 0) ? Qp : Kp;
        gemm32_core<bf16, false>(A, W, bi, C, 4096, 1024, 1024);
    }
}

// ---- output GEMM with fused split-K combine in the A-staging ----
// 64x128 tile. A[row=token][col=dmodel] = (sum_sp Op[sp]) / (sum_sp L[sp]),
// built on the fly and ds_written into the swizzled LDS layout.
// Grid 512 flat, swizzled: xt = id & 63 (same-A blocks share an XCD).
__global__ __launch_bounds__(256) void gemm_out_fused(
    const bf16* __restrict__ Op, const float* __restrict__ Lp,
    const bf16* __restrict__ W, const float* __restrict__ bias,
    float* __restrict__ C) {
    __shared__ bf16 Asm[64 * 64];
    __shared__ bf16 Bsm[128 * 64];
    const int id = blockIdx.x;
    const int m0 = (id & 63) * 64;
    const int n0 = (id >> 6) * 128;
    const int lane = threadIdx.x & 63;
    const int w = threadIdx.x >> 6;
    const int l31 = lane & 31;
    const int h = lane >> 5;
    const int x7 = l31 & 7;
    const int srow = lane >> 3;
    const int l7 = lane & 7;
    const int scol = (l7 ^ srow) * 8;
    const int wm = (w & 1) * 32;
    const int wn = (w >> 1) * 64;

    f32x16 acc[2] = {};

    for (int k0 = 0; k0 < 1024; k0 += 64) {
        // A staging: combine 4 split-K partials, normalize, swizzled ds_write
#pragma unroll
        for (int c = 0; c < 2; ++c) {
            int r = w * 16 + c * 8;
            int row = m0 + r + srow;             // token
            int colb = k0 + scol;                // dmodel col base (8-aligned)
            int b = row >> 11, q = row & 2047;
            int hh = colb >> 6, d = colb & 63;
            size_t l0i = (size_t)(b * 16 + hh) * 2048 + q;
            bf16x8 v0 = *(const bf16x8*)&Op[(l0i + 0ull * 65536) * 64 + d];
            bf16x8 v1 = *(const bf16x8*)&Op[(l0i + 1ull * 65536) * 64 + d];
            bf16x8 v2 = *(const bf16x8*)&Op[(l0i + 2ull * 65536) * 64 + d];
            bf16x8 v3 = *(const bf16x8*)&Op[(l0i + 3ull * 65536) * 64 + d];
            float inv = 1.0f / ((Lp[l0i] + Lp[l0i + 65536]) +
                                (Lp[l0i + 2 * 65536] + Lp[l0i + 3 * 65536]));
            bf16x8 o;
#pragma unroll
            for (int i = 0; i < 8; ++i)
                o[i] = (bf16)((((float)v0[i] + (float)v1[i]) +
                               ((float)v2[i] + (float)v3[i])) * inv);
            *(bf16x8*)&Asm[(r + srow) * 64 + l7 * 8] = o;
        }
#pragma unroll
        for (int c = 0; c < 4; ++c) {
            int r = w * 32 + c * 8;
            gload_lds16(W + (size_t)(n0 + r + srow) * 1024 + k0 + scol, &Bsm[r * 64]);
        }
        __syncthreads();
#pragma unroll
        for (int step = 0; step < 4; ++step) {
            bf16x8 af = *(const bf16x8*)&Asm[(wm + l31) * 64 +
                                             (((step * 2 + h) ^ x7) * 8)];
            bf16x8 bfv[2];
#pragma unroll
            for (int j = 0; j < 2; ++j)
                bfv[j] = *(const bf16x8*)&Bsm[(wn + j * 32 + l31) * 64 +
                                              (((step * 2 + h) ^ x7) * 8)];
#pragma unroll
            for (int j = 0; j < 2; ++j)
                acc[j] = __builtin_amdgcn_mfma_f32_32x32x16_bf16(af, bfv[j],
                                                                 acc[j], 0, 0, 0);
        }
        __syncthreads();
    }
#pragma unroll
    for (int j = 0; j < 2; ++j) {
        int col = n0 + wn + j * 32 + l31;
        float bv = bias[col];
#pragma unroll
        for (int g = 0; g < 4; ++g)
#pragma unroll
            for (int rr = 0; rr < 4; ++rr) {
                int row = m0 + wm + rr + g * 8 + 4 * h;
                C[(size_t)row * 1024 + col] = acc[j][g * 4 + rr] + bv;
            }
    }
}

// ---------------- flash attention v5: split-K=4 ----------------
// Block: 256 q (4 waves x 64q), one (b,h), 1/4 of keys (512).
// Grid 1024 flat, XCD-swizzled: g = qb*128 + bh*4 + sp, so blocks sharing
// (bh,sp) K/V differ by multiples of 128 -> same XCD -> K/V L2 reuse.
// 4 blocks/CU (LDS 4x32=128KB, VGPR<=128 via launch_bounds(256,4)) for
// latency hiding of the MFMA->softmax->MFMA chain.
// Double-buffered K/V LDS, single barrier/iter, prefetch after barrier.
__global__ __launch_bounds__(256, 4) void attn_k(
    const bf16* __restrict__ Qp, const bf16* __restrict__ Kp,
    const bf16* __restrict__ VpT, const float* __restrict__ mb,
    bf16* __restrict__ Opart, float* __restrict__ Lpart) {
    __shared__ bf16 KV[2][2][64 * 64];  // [buf][K|V][.]
    const int g = blockIdx.x;
    const int qb = g >> 7;          // 0..7
    const int bh = (g & 127) >> 2;  // 0..31
    const int sp = g & 3;           // 0..3
    const int b = bh >> 4, hh = bh & 15;
    const int lane = threadIdx.x & 63, w = threadIdx.x >> 6;
    const int l31 = lane & 31, h = lane >> 5;
    const int x7 = l31 & 7;
    const int srow = lane >> 3, scol = ((lane & 7) ^ srow) * 8;
    const float SC = 0.125f * 1.44269504f;
    const int q0 = qb * 256;
    const int k0 = sp * 512;

    const bf16* Kg = Kp + (size_t)(b * 2048) * 1024 + hh * 64;
    const bf16* Vg = VpT + (size_t)bh * 64 * 2048;
    const float* mbb = mb + b * 2048;

    auto stage = [&](int buf, int kt) {
#pragma unroll
        for (int c = 0; c < 2; ++c) {
            int r = w * 16 + c * 8;
            gload_lds16(Kg + (size_t)(kt + r + srow) * 1024 + scol,
                        &KV[buf][0][r * 64]);
            gload_lds16(Vg + (size_t)(r + srow) * 2048 + kt + scol,
                        &KV[buf][1][r * 64]);
        }
    };
    stage(0, k0);

    // Q B-frags for both 32-q groups: B[n=q][k=d]
    bf16x8 qf[2][4];
#pragma unroll
    for (int qg = 0; qg < 2; ++qg) {
        const bf16* Qbase =
            Qp + (size_t)(b * 2048 + q0 + w * 64 + qg * 32 + l31) * 1024 + hh * 64;
#pragma unroll
        for (int step = 0; step < 4; ++step)
            qf[qg][step] = *(const bf16x8*)(Qbase + step * 16 + h * 8);
    }

    f32x16 o[2][2] = {};  // [qg][d-group]
    float lsum[2] = {0.0f, 0.0f};

    for (int it = 0; it < 8; ++it) {
        __syncthreads();  // drains stage(it); prefetch below overlaps compute
        if (it < 7) stage((it + 1) & 1, k0 + (it + 1) * 64);
        const bf16* Ks = KV[it & 1][0];
        const bf16* Vs = KV[it & 1][1];
        const int kt = k0 + it * 64;

        bf16x8 pa[2][4];
#pragma unroll
        for (int kg = 0; kg < 2; ++kg) {
            f32x16 z0 = {}, z1 = {};
            __builtin_amdgcn_s_setprio(1);
#pragma unroll
            for (int step = 0; step < 4; ++step) {
                bf16x8 kf = *(const bf16x8*)&Ks[(kg * 32 + l31) * 64 +
                                                (((step * 2 + h) ^ x7) * 8)];
                z0 = __builtin_amdgcn_mfma_f32_32x32x16_bf16(kf, qf[0][step], z0, 0, 0, 0);
                z1 = __builtin_amdgcn_mfma_f32_32x32x16_bf16(kf, qf[1][step], z1, 0, 0, 0);
            }
            __builtin_amdgcn_s_setprio(0);
#pragma unroll
            for (int g = 0; g < 4; ++g) {
                float4 bia = *(const float4*)&mbb[kt + kg * 32 + g * 8 + 4 * h];
#pragma unroll
                for (int qg = 0; qg < 2; ++qg) {
                    const f32x16& z = qg ? z1 : z0;
                    float p0 = __builtin_amdgcn_exp2f(fmaf(z[g * 4 + 0], SC, bia.x));
                    float p1 = __builtin_amdgcn_exp2f(fmaf(z[g * 4 + 1], SC, bia.y));
                    float p2 = __builtin_amdgcn_exp2f(fmaf(z[g * 4 + 2], SC, bia.z));
                    float p3 = __builtin_amdgcn_exp2f(fmaf(z[g * 4 + 3], SC, bia.w));
                    lsum[qg] += (p0 + p1) + (p2 + p3);
                    bf16x8& pf = pa[qg][kg * 2 + (g >> 1)];
                    int jb = (g & 1) * 4;
                    pf[jb + 0] = (bf16)p0;
                    pf[jb + 1] = (bf16)p1;
                    pf[jb + 2] = (bf16)p2;
                    pf[jb + 3] = (bf16)p3;
                }
            }
        }
        // O[q][d] += P V : A = P C-regs (key-permuted), B = permuted VpT frags
        __builtin_amdgcn_s_setprio(1);
#pragma unroll
        for (int t = 0; t < 2; ++t)
#pragma unroll
            for (int kk = 0; kk < 4; ++kk) {
                bf16x8 vf = *(const bf16x8*)&Vs[(t * 32 + l31) * 64 +
                                                (((kk * 2 + h) ^ x7) * 8)];
                o[0][t] = __builtin_amdgcn_mfma_f32_32x32x16_bf16(pa[0][kk], vf, o[0][t], 0, 0, 0);
                o[1][t] = __builtin_amdgcn_mfma_f32_32x32x16_bf16(pa[1][kk], vf, o[1][t], 0, 0, 0);
            }
        __builtin_amdgcn_s_setprio(0);
    }

    // store partials (unnormalized O bf16 + lsum fp32)
    const size_t pbase = (size_t)(sp * 32 + bh) * 2048;
#pragma unroll
    for (int qg = 0; qg < 2; ++qg) {
        float ls = lsum[qg] + __shfl_xor(lsum[qg], 32, 64);
        if (h == 0)
            Lpart[pbase + q0 + w * 64 + qg * 32 + l31] = ls;
#pragma unroll
        for (int t = 0; t < 2; ++t)
#pragma unroll
            for (int g = 0; g < 4; ++g)
#pragma unroll
                for (int rr = 0; rr < 4; ++rr) {
                    int q = q0 + w * 64 + qg * 32 + rr + g * 8 + 4 * h;
                    Opart[(pbase + q) * 64 + t * 32 + l31] =
                        (bf16)o[qg][t][g * 4 + rr];
                }
    }
}

extern "C" void kernel_launch(void* const* d_in, const int* in_sizes, int n_in,
                              void* d_out, int out_size, void* d_ws, size_t ws_size,
                              hipStream_t stream) {
    const float* q   = (const float*)d_in[0];
    const float* kt  = (const float*)d_in[1];
    const float* v   = (const float*)d_in[2];
    const int* mask  = (const int*)d_in[3];
    const float* Wq  = (const float*)d_in[4];
    const float* bq  = (const float*)d_in[5];
    const float* Wk  = (const float*)d_in[6];
    const float* bk  = (const float*)d_in[7];
    const float* Wv  = (const float*)d_in[8];
    const float* bv  = (const float*)d_in[9];
    const float* Wo  = (const float*)d_in[10];
    const float* bo  = (const float*)d_in[11];
    float* out = (float*)d_out;

    char* ws = (char*)d_ws;
    const size_t SZ_IN = 4096ull * 1024 * 2;  // 8 MB bf16 activation
    const size_t SZ_W  = 1024ull * 1024 * 2;  // 2 MB bf16 weight
    bf16* qb  = (bf16*)(ws + 0 * SZ_IN);
    bf16* kb  = (bf16*)(ws + 1 * SZ_IN);
    bf16* vb  = (bf16*)(ws + 2 * SZ_IN);
    bf16* Wqb = (bf16*)(ws + 3 * SZ_IN);
    bf16* Wkb = (bf16*)(ws + 3 * SZ_IN + 1 * SZ_W);
    bf16* Wvb = (bf16*)(ws + 3 * SZ_IN + 2 * SZ_W);
    bf16* Wob = (bf16*)(ws + 3 * SZ_IN + 3 * SZ_W);
    bf16* Qp  = (bf16*)(ws + 3 * SZ_IN + 4 * SZ_W);
    bf16* Kp  = (bf16*)(ws + 4 * SZ_IN + 4 * SZ_W);
    bf16* VpT = (bf16*)(ws + 5 * SZ_IN + 4 * SZ_W);
    float* mb = (float*)(ws + 6 * SZ_IN + 4 * SZ_W);          // 16 KB (pad 1 MB)
    char*  p0 = ws + 6 * SZ_IN + 4 * SZ_W + (1 << 20);
    bf16* Opart = (bf16*)p0;                                   // 4*32*2048*64*2 = 33.6 MB
    float* Lpart = (float*)(p0 + 4ull * 32 * 2048 * 64 * 2);   // 1 MB

    const int NIN = 4096 * 1024, NW = 1024 * 1024;
    cast8_k<<<dim3(NIN / 2048, 1, 8), 256, 0, stream>>>(
        q, kt, v, Wq, Wk, Wv, Wo, qb, kb, vb, Wqb, Wkb, Wvb, Wob,
        mask, mb, NIN, NW);

    gemm_qkv<<<dim3(32, 8, 3), 256, 0, stream>>>(qb, kb, vb, Wqb, Wkb, Wvb,
                                                 bq, bk, bv, Qp, Kp, VpT);
    attn_k<<<dim3(1024), 256, 0, stream>>>(Qp, Kp, VpT, mb, Opart, Lpart);
    gemm_out_fused<<<dim3(512), 256, 0, stream>>>(Opart, Lpart, Wob, bo, out);
}

// Round 2
// 232.774 us; speedup vs baseline: 1.7081x; 1.7081x over previous
//
#include <hip/hip_runtime.h>
#include <hip/hip_bf16.h>

typedef __bf16 bf16;
typedef __bf16 bf16x8 __attribute__((ext_vector_type(8)));
typedef __bf16 bf16x4 __attribute__((ext_vector_type(4)));
typedef float  f32x4  __attribute__((ext_vector_type(4)));
typedef float  f32x16 __attribute__((ext_vector_type(16)));

#define AS1 __attribute__((address_space(1)))
#define AS3 __attribute__((address_space(3)))

__device__ __forceinline__ void gload_lds16(const bf16* g, bf16* l) {
    __builtin_amdgcn_global_load_lds((const AS1 unsigned int*)g,
                                     (AS3 unsigned int*)l, 16, 0, 0);
}

// ------- cast fp32 -> bf16 (7 tensors) + mask bias, via grid.z -------
__global__ __launch_bounds__(256) void cast8_k(
    const float* __restrict__ s0, const float* __restrict__ s1,
    const float* __restrict__ s2, const float* __restrict__ s3,
    const float* __restrict__ s4, const float* __restrict__ s5,
    const float* __restrict__ s6,
    bf16* __restrict__ d0, bf16* __restrict__ d1, bf16* __restrict__ d2,
    bf16* __restrict__ d3, bf16* __restrict__ d4, bf16* __restrict__ d5,
    bf16* __restrict__ d6,
    const int* __restrict__ m, float* __restrict__ mb,
    int n_big, int n_small) {
    int z = blockIdx.z;
    int i = (blockIdx.x * 256 + threadIdx.x) * 8;
    if (z == 7) {  // mask -> exp2-domain additive bias
        if (i >= 4096) return;
        int4 a = *(const int4*)(m + i);
        int4 b = *(const int4*)(m + i + 4);
        float4 o0, o1;
        o0.x = (a.x == 0) ? -1.442695e9f : -17.3123405f;
        o0.y = (a.y == 0) ? -1.442695e9f : -17.3123405f;
        o0.z = (a.z == 0) ? -1.442695e9f : -17.3123405f;
        o0.w = (a.w == 0) ? -1.442695e9f : -17.3123405f;
        o1.x = (b.x == 0) ? -1.442695e9f : -17.3123405f;
        o1.y = (b.y == 0) ? -1.442695e9f : -17.3123405f;
        o1.z = (b.z == 0) ? -1.442695e9f : -17.3123405f;
        o1.w = (b.w == 0) ? -1.442695e9f : -17.3123405f;
        *(float4*)(mb + i) = o0;
        *(float4*)(mb + i + 4) = o1;
        return;
    }
    const float* s = (z == 0) ? s0 : (z == 1) ? s1 : (z == 2) ? s2
                   : (z == 3) ? s3 : (z == 4) ? s4 : (z == 5) ? s5 : s6;
    bf16* d = (z == 0) ? d0 : (z == 1) ? d1 : (z == 2) ? d2
            : (z == 3) ? d3 : (z == 4) ? d4 : (z == 5) ? d5 : d6;
    int n = (z < 3) ? n_big : n_small;
    if (i >= n) return;
    float4 a = *(const float4*)(s + i);
    float4 b = *(const float4*)(s + i + 4);
    bf16x8 o;
    o[0] = (bf16)a.x; o[1] = (bf16)a.y; o[2] = (bf16)a.z; o[3] = (bf16)a.w;
    o[4] = (bf16)b.x; o[5] = (bf16)b.y; o[6] = (bf16)b.z; o[7] = (bf16)b.w;
    *(bf16x8*)(d + i) = o;
}

// ---------------- BT-GEMM, 32x32x16 MFMA, 128x128 tile ----------------
// TRANS=true: compute C^T and store to VpT with the bit2<->bit3 key
// permutation baked in (for attn's PV A-frag trick).
template <typename OUT_T, bool TRANS>
__device__ __forceinline__ void gemm32_core(
    const bf16* __restrict__ A, const bf16* __restrict__ W,
    const float* __restrict__ bias, OUT_T* __restrict__ C,
    int M, int N, int K) {
    __shared__ bf16 Asm[128 * 64];
    __shared__ bf16 Bsm[128 * 64];
    const int lane = threadIdx.x & 63;
    const int w = threadIdx.x >> 6;
    const int l31 = lane & 31;
    const int h = lane >> 5;
    const int x7 = l31 & 7;
    const int m0 = blockIdx.x * 128;
    const int n0 = blockIdx.y * 128;
    const int srow = lane >> 3;
    const int scol = ((lane & 7) ^ srow) * 8;
    const int wm = (w & 1) * 64;
    const int wn = (w >> 1) * 64;

    f32x16 acc[2][2] = {};

    for (int k0 = 0; k0 < K; k0 += 64) {
#pragma unroll
        for (int c = 0; c < 4; ++c) {
            int r = w * 32 + c * 8;
            gload_lds16(A + (size_t)(m0 + r + srow) * K + k0 + scol, &Asm[r * 64]);
            gload_lds16(W + (size_t)(n0 + r + srow) * K + k0 + scol, &Bsm[r * 64]);
        }
        __syncthreads();
#pragma unroll
        for (int step = 0; step < 4; ++step) {
            bf16x8 af[2], bfv[2];
#pragma unroll
            for (int i = 0; i < 2; ++i)
                af[i] = *(const bf16x8*)&Asm[(wm + i * 32 + l31) * 64 +
                                             (((step * 2 + h) ^ x7) * 8)];
#pragma unroll
            for (int j = 0; j < 2; ++j)
                bfv[j] = *(const bf16x8*)&Bsm[(wn + j * 32 + l31) * 64 +
                                              (((step * 2 + h) ^ x7) * 8)];
#pragma unroll
            for (int i = 0; i < 2; ++i)
#pragma unroll
                for (int j = 0; j < 2; ++j)
                    acc[i][j] = TRANS
                        ? __builtin_amdgcn_mfma_f32_32x32x16_bf16(bfv[j], af[i],
                                                                  acc[i][j], 0, 0, 0)
                        : __builtin_amdgcn_mfma_f32_32x32x16_bf16(af[i], bfv[j],
                                                                  acc[i][j], 0, 0, 0);
        }
        __syncthreads();
    }
    if (!TRANS) {
#pragma unroll
        for (int i = 0; i < 2; ++i)
#pragma unroll
            for (int j = 0; j < 2; ++j) {
                int col = n0 + wn + j * 32 + l31;
                float bv = bias[col];
#pragma unroll
                for (int g = 0; g < 4; ++g)
#pragma unroll
                    for (int rr = 0; rr < 4; ++rr) {
                        int row = m0 + wm + i * 32 + rr + g * 8 + 4 * h;
                        C[(size_t)row * N + col] =
                            (OUT_T)(acc[i][j][g * 4 + rr] + bv);
                    }
            }
    } else {
#pragma unroll
        for (int i = 0; i < 2; ++i) {
            int s = m0 + wm + i * 32 + l31;
            int b = s >> 11;
            int sl = s & 2047;
            int sp = (sl & ~12) | ((sl & 4) << 1) | ((sl & 8) >> 1);
#pragma unroll
            for (int j = 0; j < 2; ++j)
#pragma unroll
                for (int g = 0; g < 4; ++g) {
                    float4 bv4 = *(const float4*)&bias[n0 + wn + j * 32 + g * 8 + 4 * h];
#pragma unroll
                    for (int rr = 0; rr < 4; ++rr) {
                        int n = n0 + wn + j * 32 + g * 8 + 4 * h + rr;
                        C[(size_t)(b * 1024 + n) * 2048 + sp] =
                            (OUT_T)(acc[i][j][g * 4 + rr] + (&bv4.x)[rr]);
                    }
                }
        }
    }
}

__global__ __launch_bounds__(256) void gemm_qkv(
    const bf16* __restrict__ qb, const bf16* __restrict__ kb, const bf16* __restrict__ vb,
    const bf16* __restrict__ Wq, const bf16* __restrict__ Wk, const bf16* __restrict__ Wv,
    const float* __restrict__ bq, const float* __restrict__ bk, const float* __restrict__ bv,
    bf16* __restrict__ Qp, bf16* __restrict__ Kp, bf16* __restrict__ VpT) {
    int z = blockIdx.z;
    if (z == 2) {
        gemm32_core<bf16, true>(vb, Wv, bv, VpT, 4096, 1024, 1024);
    } else {
        const bf16* A = (z == 0) ? qb : kb;
        const bf16* W = (z == 0) ? Wq : Wk;
        const float* bi = (z == 0) ? bq : bk;
        bf16* C = (z == 0) ? Qp : Kp;
        gemm32_core<bf16, false>(A, W, bi, C, 4096, 1024, 1024);
    }
}

// ---- output GEMM with fused split-K combine in the A-staging ----
// 64x128 tile. A[row=token][col=dmodel] = (sum_sp Op[sp]) / (sum_sp L[sp]),
// built on the fly and ds_written into the swizzled LDS layout.
// Grid 512 flat, swizzled: xt = id & 63 (same-A blocks share an XCD).
__global__ __launch_bounds__(256) void gemm_out_fused(
    const bf16* __restrict__ Op, const float* __restrict__ Lp,
    const bf16* __restrict__ W, const float* __restrict__ bias,
    float* __restrict__ C) {
    __shared__ bf16 Asm[64 * 64];
    __shared__ bf16 Bsm[128 * 64];
    const int id = blockIdx.x;
    const int m0 = (id & 63) * 64;
    const int n0 = (id >> 6) * 128;
    const int lane = threadIdx.x & 63;
    const int w = threadIdx.x >> 6;
    const int l31 = lane & 31;
    const int h = lane >> 5;
    const int x7 = l31 & 7;
    const int srow = lane >> 3;
    const int l7 = lane & 7;
    const int scol = (l7 ^ srow) * 8;
    const int wm = (w & 1) * 32;
    const int wn = (w >> 1) * 64;

    f32x16 acc[2] = {};

    for (int k0 = 0; k0 < 1024; k0 += 64) {
        // A staging: combine 4 split-K partials, normalize, swizzled ds_write
#pragma unroll
        for (int c = 0; c < 2; ++c) {
            int r = w * 16 + c * 8;
            int row = m0 + r + srow;             // token
            int colb = k0 + scol;                // dmodel col base (8-aligned)
            int b = row >> 11, q = row & 2047;
            int hh = colb >> 6, d = colb & 63;
            size_t l0i = (size_t)(b * 16 + hh) * 2048 + q;
            bf16x8 v0 = *(const bf16x8*)&Op[(l0i + 0ull * 65536) * 64 + d];
            bf16x8 v1 = *(const bf16x8*)&Op[(l0i + 1ull * 65536) * 64 + d];
            bf16x8 v2 = *(const bf16x8*)&Op[(l0i + 2ull * 65536) * 64 + d];
            bf16x8 v3 = *(const bf16x8*)&Op[(l0i + 3ull * 65536) * 64 + d];
            float inv = 1.0f / ((Lp[l0i] + Lp[l0i + 65536]) +
                                (Lp[l0i + 2 * 65536] + Lp[l0i + 3 * 65536]));
            bf16x8 o;
#pragma unroll
            for (int i = 0; i < 8; ++i)
                o[i] = (bf16)((((float)v0[i] + (float)v1[i]) +
                               ((float)v2[i] + (float)v3[i])) * inv);
            *(bf16x8*)&Asm[(r + srow) * 64 + l7 * 8] = o;
        }
#pragma unroll
        for (int c = 0; c < 4; ++c) {
            int r = w * 32 + c * 8;
            gload_lds16(W + (size_t)(n0 + r + srow) * 1024 + k0 + scol, &Bsm[r * 64]);
        }
        __syncthreads();
#pragma unroll
        for (int step = 0; step < 4; ++step) {
            bf16x8 af = *(const bf16x8*)&Asm[(wm + l31) * 64 +
                                             (((step * 2 + h) ^ x7) * 8)];
            bf16x8 bfv[2];
#pragma unroll
            for (int j = 0; j < 2; ++j)
                bfv[j] = *(const bf16x8*)&Bsm[(wn + j * 32 + l31) * 64 +
                                              (((step * 2 + h) ^ x7) * 8)];
#pragma unroll
            for (int j = 0; j < 2; ++j)
                acc[j] = __builtin_amdgcn_mfma_f32_32x32x16_bf16(af, bfv[j],
                                                                 acc[j], 0, 0, 0);
        }
        __syncthreads();
    }
#pragma unroll
    for (int j = 0; j < 2; ++j) {
        int col = n0 + wn + j * 32 + l31;
        float bv = bias[col];
#pragma unroll
        for (int g = 0; g < 4; ++g)
#pragma unroll
            for (int rr = 0; rr < 4; ++rr) {
                int row = m0 + wm + rr + g * 8 + 4 * h;
                C[(size_t)row * 1024 + col] = acc[j][g * 4 + rr] + bv;
            }
    }
}

// ---------------- flash attention v6: split-K=4, natural regalloc ----------------
// Block: 256 q (4 waves x 64q), one (b,h), 1/4 of keys (512).
// Grid 1024 flat, XCD-swizzled: g = qb*128 + bh*4 + sp, so blocks sharing
// (bh,sp) K/V differ by multiples of 128 -> same XCD -> K/V L2 reuse.
// launch_bounds(256,2): natural VGPR ~124 -> HW gives 4 waves/SIMD
// (512/124) = 4 blocks/CU with grid 1024. Do NOT declare (256,4): that
// caps the budget at 128 arch-VGPRs < live state (o64+qf32+pa32) and
// spills accumulators to scratch (~900 MB HBM traffic, round-1 regression).
// Double-buffered K/V LDS, single barrier/iter, prefetch after barrier.
__global__ __launch_bounds__(256, 2) void attn_k(
    const bf16* __restrict__ Qp, const bf16* __restrict__ Kp,
    const bf16* __restrict__ VpT, const float* __restrict__ mb,
    bf16* __restrict__ Opart, float* __restrict__ Lpart) {
    __shared__ bf16 KV[2][2][64 * 64];  // [buf][K|V][.]
    const int g = blockIdx.x;
    const int qb = g >> 7;          // 0..7
    const int bh = (g & 127) >> 2;  // 0..31
    const int sp = g & 3;           // 0..3
    const int b = bh >> 4, hh = bh & 15;
    const int lane = threadIdx.x & 63, w = threadIdx.x >> 6;
    const int l31 = lane & 31, h = lane >> 5;
    const int x7 = l31 & 7;
    const int srow = lane >> 3, scol = ((lane & 7) ^ srow) * 8;
    const float SC = 0.125f * 1.44269504f;
    const int q0 = qb * 256;
    const int k0 = sp * 512;

    const bf16* Kg = Kp + (size_t)(b * 2048) * 1024 + hh * 64;
    const bf16* Vg = VpT + (size_t)bh * 64 * 2048;
    const float* mbb = mb + b * 2048;

    auto stage = [&](int buf, int kt) {
#pragma unroll
        for (int c = 0; c < 2; ++c) {
            int r = w * 16 + c * 8;
            gload_lds16(Kg + (size_t)(kt + r + srow) * 1024 + scol,
                        &KV[buf][0][r * 64]);
            gload_lds16(Vg + (size_t)(r + srow) * 2048 + kt + scol,
                        &KV[buf][1][r * 64]);
        }
    };
    stage(0, k0);

    // Q B-frags for both 32-q groups: B[n=q][k=d]
    bf16x8 qf[2][4];
#pragma unroll
    for (int qg = 0; qg < 2; ++qg) {
        const bf16* Qbase =
            Qp + (size_t)(b * 2048 + q0 + w * 64 + qg * 32 + l31) * 1024 + hh * 64;
#pragma unroll
        for (int step = 0; step < 4; ++step)
            qf[qg][step] = *(const bf16x8*)(Qbase + step * 16 + h * 8);
    }

    f32x16 o[2][2] = {};  // [qg][d-group]
    float lsum[2] = {0.0f, 0.0f};

    for (int it = 0; it < 8; ++it) {
        __syncthreads();  // drains stage(it); prefetch below overlaps compute
        if (it < 7) stage((it + 1) & 1, k0 + (it + 1) * 64);
        const bf16* Ks = KV[it & 1][0];
        const bf16* Vs = KV[it & 1][1];
        const int kt = k0 + it * 64;

        bf16x8 pa[2][4];
#pragma unroll
        for (int kg = 0; kg < 2; ++kg) {
            f32x16 z0 = {}, z1 = {};
            __builtin_amdgcn_s_setprio(1);
#pragma unroll
            for (int step = 0; step < 4; ++step) {
                bf16x8 kf = *(const bf16x8*)&Ks[(kg * 32 + l31) * 64 +
                                                (((step * 2 + h) ^ x7) * 8)];
                z0 = __builtin_amdgcn_mfma_f32_32x32x16_bf16(kf, qf[0][step], z0, 0, 0, 0);
                z1 = __builtin_amdgcn_mfma_f32_32x32x16_bf16(kf, qf[1][step], z1, 0, 0, 0);
            }
            __builtin_amdgcn_s_setprio(0);
#pragma unroll
            for (int g = 0; g < 4; ++g) {
                float4 bia = *(const float4*)&mbb[kt + kg * 32 + g * 8 + 4 * h];
#pragma unroll
                for (int qg = 0; qg < 2; ++qg) {
                    const f32x16& z = qg ? z1 : z0;
                    float p0 = __builtin_amdgcn_exp2f(fmaf(z[g * 4 + 0], SC, bia.x));
                    float p1 = __builtin_amdgcn_exp2f(fmaf(z[g * 4 + 1], SC, bia.y));
                    float p2 = __builtin_amdgcn_exp2f(fmaf(z[g * 4 + 2], SC, bia.z));
                    float p3 = __builtin_amdgcn_exp2f(fmaf(z[g * 4 + 3], SC, bia.w));
                    lsum[qg] += (p0 + p1) + (p2 + p3);
                    bf16x8& pf = pa[qg][kg * 2 + (g >> 1)];
                    int jb = (g & 1) * 4;
                    pf[jb + 0] = (bf16)p0;
                    pf[jb + 1] = (bf16)p1;
                    pf[jb + 2] = (bf16)p2;
                    pf[jb + 3] = (bf16)p3;
                }
            }
        }
        // O[q][d] += P V : A = P C-regs (key-permuted), B = permuted VpT frags
        __builtin_amdgcn_s_setprio(1);
#pragma unroll
        for (int t = 0; t < 2; ++t)
#pragma unroll
            for (int kk = 0; kk < 4; ++kk) {
                bf16x8 vf = *(const bf16x8*)&Vs[(t * 32 + l31) * 64 +
                                                (((kk * 2 + h) ^ x7) * 8)];
                o[0][t] = __builtin_amdgcn_mfma_f32_32x32x16_bf16(pa[0][kk], vf, o[0][t], 0, 0, 0);
                o[1][t] = __builtin_amdgcn_mfma_f32_32x32x16_bf16(pa[1][kk], vf, o[1][t], 0, 0, 0);
            }
        __builtin_amdgcn_s_setprio(0);
    }

    // store partials (unnormalized O bf16 + lsum fp32)
    const size_t pbase = (size_t)(sp * 32 + bh) * 2048;
#pragma unroll
    for (int qg = 0; qg < 2; ++qg) {
        float ls = lsum[qg] + __shfl_xor(lsum[qg], 32, 64);
        if (h == 0)
            Lpart[pbase + q0 + w * 64 + qg * 32 + l31] = ls;
#pragma unroll
        for (int t = 0; t < 2; ++t)
#pragma unroll
            for (int g = 0; g < 4; ++g)
#pragma unroll
                for (int rr = 0; rr < 4; ++rr) {
                    int q = q0 + w * 64 + qg * 32 + rr + g * 8 + 4 * h;
                    Opart[(pbase + q) * 64 + t * 32 + l31] =
                        (bf16)o[qg][t][g * 4 + rr];
                }
    }
}

extern "C" void kernel_launch(void* const* d_in, const int* in_sizes, int n_in,
                              void* d_out, int out_size, void* d_ws, size_t ws_size,
                              hipStream_t stream) {
    const float* q   = (const float*)d_in[0];
    const float* kt  = (const float*)d_in[1];
    const float* v   = (const float*)d_in[2];
    const int* mask  = (const int*)d_in[3];
    const float* Wq  = (const float*)d_in[4];
    const float* bq  = (const float*)d_in[5];
    const float* Wk  = (const float*)d_in[6];
    const float* bk  = (const float*)d_in[7];
    const float* Wv  = (const float*)d_in[8];
    const float* bv  = (const float*)d_in[9];
    const float* Wo  = (const float*)d_in[10];
    const float* bo  = (const float*)d_in[11];
    float* out = (float*)d_out;

    char* ws = (char*)d_ws;
    const size_t SZ_IN = 4096ull * 1024 * 2;  // 8 MB bf16 activation
    const size_t SZ_W  = 1024ull * 1024 * 2;  // 2 MB bf16 weight
    bf16* qb  = (bf16*)(ws + 0 * SZ_IN);
    bf16* kb  = (bf16*)(ws + 1 * SZ_IN);
    bf16* vb  = (bf16*)(ws + 2 * SZ_IN);
    bf16* Wqb = (bf16*)(ws + 3 * SZ_IN);
    bf16* Wkb = (bf16*)(ws + 3 * SZ_IN + 1 * SZ_W);
    bf16* Wvb = (bf16*)(ws + 3 * SZ_IN + 2 * SZ_W);
    bf16* Wob = (bf16*)(ws + 3 * SZ_IN + 3 * SZ_W);
    bf16* Qp  = (bf16*)(ws + 3 * SZ_IN + 4 * SZ_W);
    bf16* Kp  = (bf16*)(ws + 4 * SZ_IN + 4 * SZ_W);
    bf16* VpT = (bf16*)(ws + 5 * SZ_IN + 4 * SZ_W);
    float* mb = (float*)(ws + 6 * SZ_IN + 4 * SZ_W);          // 16 KB (pad 1 MB)
    char*  p0 = ws + 6 * SZ_IN + 4 * SZ_W + (1 << 20);
    bf16* Opart = (bf16*)p0;                                   // 4*32*2048*64*2 = 33.6 MB
    float* Lpart = (float*)(p0 + 4ull * 32 * 2048 * 64 * 2);   // 1 MB

    const int NIN = 4096 * 1024, NW = 1024 * 1024;
    cast8_k<<<dim3(NIN / 2048, 1, 8), 256, 0, stream>>>(
        q, kt, v, Wq, Wk, Wv, Wo, qb, kb, vb, Wqb, Wkb, Wvb, Wob,
        mask, mb, NIN, NW);

    gemm_qkv<<<dim3(32, 8, 3), 256, 0, stream>>>(qb, kb, vb, Wqb, Wkb, Wvb,
                                                 bq, bk, bv, Qp, Kp, VpT);
    attn_k<<<dim3(1024), 256, 0, stream>>>(Qp, Kp, VpT, mb, Opart, Lpart);
    gemm_out_fused<<<dim3(512), 256, 0, stream>>>(Opart, Lpart, Wob, bo, out);
}

// Round 3
// 227.831 us; speedup vs baseline: 1.7451x; 1.0217x over previous
//
#include <hip/hip_runtime.h>
#include <hip/hip_bf16.h>

typedef __bf16 bf16;
typedef __bf16 bf16x8 __attribute__((ext_vector_type(8)));
typedef __bf16 bf16x4 __attribute__((ext_vector_type(4)));
typedef float  f32x4  __attribute__((ext_vector_type(4)));
typedef float  f32x16 __attribute__((ext_vector_type(16)));

#define AS1 __attribute__((address_space(1)))
#define AS3 __attribute__((address_space(3)))

__device__ __forceinline__ void gload_lds16(const bf16* g, bf16* l) {
    __builtin_amdgcn_global_load_lds((const AS1 unsigned int*)g,
                                     (AS3 unsigned int*)l, 16, 0, 0);
}

// ------- cast fp32 -> bf16 (7 tensors) + mask bias, via grid.z -------
__global__ __launch_bounds__(256) void cast8_k(
    const float* __restrict__ s0, const float* __restrict__ s1,
    const float* __restrict__ s2, const float* __restrict__ s3,
    const float* __restrict__ s4, const float* __restrict__ s5,
    const float* __restrict__ s6,
    bf16* __restrict__ d0, bf16* __restrict__ d1, bf16* __restrict__ d2,
    bf16* __restrict__ d3, bf16* __restrict__ d4, bf16* __restrict__ d5,
    bf16* __restrict__ d6,
    const int* __restrict__ m, float* __restrict__ mb,
    int n_big, int n_small) {
    int z = blockIdx.z;
    int i = (blockIdx.x * 256 + threadIdx.x) * 8;
    if (z == 7) {  // mask -> exp2-domain additive bias
        if (i >= 4096) return;
        int4 a = *(const int4*)(m + i);
        int4 b = *(const int4*)(m + i + 4);
        float4 o0, o1;
        o0.x = (a.x == 0) ? -1.442695e9f : -17.3123405f;
        o0.y = (a.y == 0) ? -1.442695e9f : -17.3123405f;
        o0.z = (a.z == 0) ? -1.442695e9f : -17.3123405f;
        o0.w = (a.w == 0) ? -1.442695e9f : -17.3123405f;
        o1.x = (b.x == 0) ? -1.442695e9f : -17.3123405f;
        o1.y = (b.y == 0) ? -1.442695e9f : -17.3123405f;
        o1.z = (b.z == 0) ? -1.442695e9f : -17.3123405f;
        o1.w = (b.w == 0) ? -1.442695e9f : -17.3123405f;
        *(float4*)(mb + i) = o0;
        *(float4*)(mb + i + 4) = o1;
        return;
    }
    const float* s = (z == 0) ? s0 : (z == 1) ? s1 : (z == 2) ? s2
                   : (z == 3) ? s3 : (z == 4) ? s4 : (z == 5) ? s5 : s6;
    bf16* d = (z == 0) ? d0 : (z == 1) ? d1 : (z == 2) ? d2
            : (z == 3) ? d3 : (z == 4) ? d4 : (z == 5) ? d5 : d6;
    int n = (z < 3) ? n_big : n_small;
    if (i >= n) return;
    float4 a = *(const float4*)(s + i);
    float4 b = *(const float4*)(s + i + 4);
    bf16x8 o;
    o[0] = (bf16)a.x; o[1] = (bf16)a.y; o[2] = (bf16)a.z; o[3] = (bf16)a.w;
    o[4] = (bf16)b.x; o[5] = (bf16)b.y; o[6] = (bf16)b.z; o[7] = (bf16)b.w;
    *(bf16x8*)(d + i) = o;
}

// ---------------- BT-GEMM, 32x32x16 MFMA, 128x128 tile ----------------
// TRANS=true: compute C^T and store to VpT with the bit2<->bit3 key
// permutation baked in (for attn's PV A-frag trick).
template <typename OUT_T, bool TRANS>
__device__ __forceinline__ void gemm32_core(
    const bf16* __restrict__ A, const bf16* __restrict__ W,
    const float* __restrict__ bias, OUT_T* __restrict__ C,
    int M, int N, int K) {
    __shared__ bf16 Asm[128 * 64];
    __shared__ bf16 Bsm[128 * 64];
    const int lane = threadIdx.x & 63;
    const int w = threadIdx.x >> 6;
    const int l31 = lane & 31;
    const int h = lane >> 5;
    const int x7 = l31 & 7;
    const int m0 = blockIdx.x * 128;
    const int n0 = blockIdx.y * 128;
    const int srow = lane >> 3;
    const int scol = ((lane & 7) ^ srow) * 8;
    const int wm = (w & 1) * 64;
    const int wn = (w >> 1) * 64;

    f32x16 acc[2][2] = {};

    for (int k0 = 0; k0 < K; k0 += 64) {
#pragma unroll
        for (int c = 0; c < 4; ++c) {
            int r = w * 32 + c * 8;
            gload_lds16(A + (size_t)(m0 + r + srow) * K + k0 + scol, &Asm[r * 64]);
            gload_lds16(W + (size_t)(n0 + r + srow) * K + k0 + scol, &Bsm[r * 64]);
        }
        __syncthreads();
#pragma unroll
        for (int step = 0; step < 4; ++step) {
            bf16x8 af[2], bfv[2];
#pragma unroll
            for (int i = 0; i < 2; ++i)
                af[i] = *(const bf16x8*)&Asm[(wm + i * 32 + l31) * 64 +
                                             (((step * 2 + h) ^ x7) * 8)];
#pragma unroll
            for (int j = 0; j < 2; ++j)
                bfv[j] = *(const bf16x8*)&Bsm[(wn + j * 32 + l31) * 64 +
                                              (((step * 2 + h) ^ x7) * 8)];
#pragma unroll
            for (int i = 0; i < 2; ++i)
#pragma unroll
                for (int j = 0; j < 2; ++j)
                    acc[i][j] = TRANS
                        ? __builtin_amdgcn_mfma_f32_32x32x16_bf16(bfv[j], af[i],
                                                                  acc[i][j], 0, 0, 0)
                        : __builtin_amdgcn_mfma_f32_32x32x16_bf16(af[i], bfv[j],
                                                                  acc[i][j], 0, 0, 0);
        }
        __syncthreads();
    }
    if (!TRANS) {
#pragma unroll
        for (int i = 0; i < 2; ++i)
#pragma unroll
            for (int j = 0; j < 2; ++j) {
                int col = n0 + wn + j * 32 + l31;
                float bv = bias[col];
#pragma unroll
                for (int g = 0; g < 4; ++g)
#pragma unroll
                    for (int rr = 0; rr < 4; ++rr) {
                        int row = m0 + wm + i * 32 + rr + g * 8 + 4 * h;
                        C[(size_t)row * N + col] =
                            (OUT_T)(acc[i][j][g * 4 + rr] + bv);
                    }
            }
    } else {
#pragma unroll
        for (int i = 0; i < 2; ++i) {
            int s = m0 + wm + i * 32 + l31;
            int b = s >> 11;
            int sl = s & 2047;
            int sp = (sl & ~12) | ((sl & 4) << 1) | ((sl & 8) >> 1);
#pragma unroll
            for (int j = 0; j < 2; ++j)
#pragma unroll
                for (int g = 0; g < 4; ++g) {
                    float4 bv4 = *(const float4*)&bias[n0 + wn + j * 32 + g * 8 + 4 * h];
#pragma unroll
                    for (int rr = 0; rr < 4; ++rr) {
                        int n = n0 + wn + j * 32 + g * 8 + 4 * h + rr;
                        C[(size_t)(b * 1024 + n) * 2048 + sp] =
                            (OUT_T)(acc[i][j][g * 4 + rr] + (&bv4.x)[rr]);
                    }
                }
        }
    }
}

__global__ __launch_bounds__(256) void gemm_qkv(
    const bf16* __restrict__ qb, const bf16* __restrict__ kb, const bf16* __restrict__ vb,
    const bf16* __restrict__ Wq, const bf16* __restrict__ Wk, const bf16* __restrict__ Wv,
    const float* __restrict__ bq, const float* __restrict__ bk, const float* __restrict__ bv,
    bf16* __restrict__ Qp, bf16* __restrict__ Kp, bf16* __restrict__ VpT) {
    int z = blockIdx.z;
    if (z == 2) {
        gemm32_core<bf16, true>(vb, Wv, bv, VpT, 4096, 1024, 1024);
    } else {
        const bf16* A = (z == 0) ? qb : kb;
        const bf16* W = (z == 0) ? Wq : Wk;
        const float* bi = (z == 0) ? bq : bk;
        bf16* C = (z == 0) ? Qp : Kp;
        gemm32_core<bf16, false>(A, W, bi, C, 4096, 1024, 1024);
    }
}

// ---- output GEMM with fused split-K combine in the A-staging ----
// 64x128 tile. A[row=token][col=dmodel] = (Op[sp0]+Op[sp1]) / (L0+L1),
// built on the fly and ds_written into the swizzled LDS layout.
// Grid 512 flat, swizzled: xt = id & 63 (same-A blocks share an XCD).
__global__ __launch_bounds__(256) void gemm_out_fused(
    const bf16* __restrict__ Op, const float* __restrict__ Lp,
    const bf16* __restrict__ W, const float* __restrict__ bias,
    float* __restrict__ C) {
    __shared__ bf16 Asm[64 * 64];
    __shared__ bf16 Bsm[128 * 64];
    const int id = blockIdx.x;
    const int m0 = (id & 63) * 64;
    const int n0 = (id >> 6) * 128;
    const int lane = threadIdx.x & 63;
    const int w = threadIdx.x >> 6;
    const int l31 = lane & 31;
    const int h = lane >> 5;
    const int x7 = l31 & 7;
    const int srow = lane >> 3;
    const int l7 = lane & 7;
    const int scol = (l7 ^ srow) * 8;
    const int wm = (w & 1) * 32;
    const int wn = (w >> 1) * 64;

    f32x16 acc[2] = {};

    for (int k0 = 0; k0 < 1024; k0 += 64) {
        // A staging: combine 2 split-K partials, normalize, swizzled ds_write
#pragma unroll
        for (int c = 0; c < 2; ++c) {
            int r = w * 16 + c * 8;
            int row = m0 + r + srow;             // token
            int colb = k0 + scol;                // dmodel col base (8-aligned)
            int b = row >> 11, q = row & 2047;
            int hh = colb >> 6, d = colb & 63;
            size_t l0i = (size_t)(b * 16 + hh) * 2048 + q;
            bf16x8 v0 = *(const bf16x8*)&Op[l0i * 64 + d];
            bf16x8 v1 = *(const bf16x8*)&Op[(l0i + 32 * 2048) * 64 + d];
            float inv = 1.0f / (Lp[l0i] + Lp[l0i + 32 * 2048]);
            bf16x8 o;
#pragma unroll
            for (int i = 0; i < 8; ++i)
                o[i] = (bf16)(((float)v0[i] + (float)v1[i]) * inv);
            *(bf16x8*)&Asm[(r + srow) * 64 + l7 * 8] = o;
        }
#pragma unroll
        for (int c = 0; c < 4; ++c) {
            int r = w * 32 + c * 8;
            gload_lds16(W + (size_t)(n0 + r + srow) * 1024 + k0 + scol, &Bsm[r * 64]);
        }
        __syncthreads();
#pragma unroll
        for (int step = 0; step < 4; ++step) {
            bf16x8 af = *(const bf16x8*)&Asm[(wm + l31) * 64 +
                                             (((step * 2 + h) ^ x7) * 8)];
            bf16x8 bfv[2];
#pragma unroll
            for (int j = 0; j < 2; ++j)
                bfv[j] = *(const bf16x8*)&Bsm[(wn + j * 32 + l31) * 64 +
                                              (((step * 2 + h) ^ x7) * 8)];
#pragma unroll
            for (int j = 0; j < 2; ++j)
                acc[j] = __builtin_amdgcn_mfma_f32_32x32x16_bf16(af, bfv[j],
                                                                 acc[j], 0, 0, 0);
        }
        __syncthreads();
    }
#pragma unroll
    for (int j = 0; j < 2; ++j) {
        int col = n0 + wn + j * 32 + l31;
        float bv = bias[col];
#pragma unroll
        for (int g = 0; g < 4; ++g)
#pragma unroll
            for (int rr = 0; rr < 4; ++rr) {
                int row = m0 + wm + rr + g * 8 + 4 * h;
                C[(size_t)row * 1024 + col] = acc[j][g * 4 + rr] + bv;
            }
    }
}

// ---------------- flash attention v7: 32q/wave, split-K=2 ----------------
// Block: 128 q (4 waves x 32q), one (b,h), 1/2 of keys (1024).
// Grid 1024 flat: qb = g>>6 (16), bh = (g>>1)&31, sp = g&1.
// Blocks sharing (bh,sp) K/V are stride-64 apart -> same XCD -> L2 reuse.
// Traffic-neutral occupancy raise vs 64q/wave: Q fetch unchanged (each Q
// row read once per sp), Opart unchanged; live regs halve to ~118 unified
// (qf16 + pa16 + o32acc + z16acc + addr) -> 4 waves/SIMD genuinely fits
// the (256,4) 128-reg cap (round-1's spill was live~180 > 128; here ~118).
// Cost: LDS-read traffic doubles (each kf/vf feeds 1 MFMA, not 2) --
// floor ~27us chip-wide, below expected wall.
// ABORT criterion: if FETCH_SIZE >> 20 MB, the cap spilled -> use (256,3).
__global__ __launch_bounds__(256, 4) void attn_k(
    const bf16* __restrict__ Qp, const bf16* __restrict__ Kp,
    const bf16* __restrict__ VpT, const float* __restrict__ mb,
    bf16* __restrict__ Opart, float* __restrict__ Lpart) {
    __shared__ bf16 KV[2][2][64 * 64];  // [buf][K|V][.]
    const int g = blockIdx.x;
    const int qb = g >> 6;          // 0..15
    const int bh = (g >> 1) & 31;   // 0..31
    const int sp = g & 1;           // 0..1
    const int b = bh >> 4, hh = bh & 15;
    const int lane = threadIdx.x & 63, w = threadIdx.x >> 6;
    const int l31 = lane & 31, h = lane >> 5;
    const int x7 = l31 & 7;
    const int srow = lane >> 3, scol = ((lane & 7) ^ srow) * 8;
    const float SC = 0.125f * 1.44269504f;
    const int q0 = qb * 128;
    const int k0 = sp * 1024;

    const bf16* Kg = Kp + (size_t)(b * 2048) * 1024 + hh * 64;
    const bf16* Vg = VpT + (size_t)bh * 64 * 2048;
    const float* mbb = mb + b * 2048;

    auto stage = [&](int buf, int kt) {
#pragma unroll
        for (int c = 0; c < 2; ++c) {
            int r = w * 16 + c * 8;
            gload_lds16(Kg + (size_t)(kt + r + srow) * 1024 + scol,
                        &KV[buf][0][r * 64]);
            gload_lds16(Vg + (size_t)(r + srow) * 2048 + kt + scol,
                        &KV[buf][1][r * 64]);
        }
    };
    stage(0, k0);

    // Q B-frags for this wave's 32 q rows: B[n=q][k=d]
    bf16x8 qf[4];
    {
        const bf16* Qbase =
            Qp + (size_t)(b * 2048 + q0 + w * 32 + l31) * 1024 + hh * 64;
#pragma unroll
        for (int step = 0; step < 4; ++step)
            qf[step] = *(const bf16x8*)(Qbase + step * 16 + h * 8);
    }

    f32x16 o[2] = {};  // [d-group]
    float lsum = 0.0f;

    for (int it = 0; it < 16; ++it) {
        __syncthreads();  // drains stage(it); prefetch below overlaps compute
        if (it < 15) stage((it + 1) & 1, k0 + (it + 1) * 64);
        const bf16* Ks = KV[it & 1][0];
        const bf16* Vs = KV[it & 1][1];
        const int kt = k0 + it * 64;

        bf16x8 pa[4];
#pragma unroll
        for (int kg = 0; kg < 2; ++kg) {
            f32x16 z = {};
            __builtin_amdgcn_s_setprio(1);
#pragma unroll
            for (int step = 0; step < 4; ++step) {
                bf16x8 kf = *(const bf16x8*)&Ks[(kg * 32 + l31) * 64 +
                                                (((step * 2 + h) ^ x7) * 8)];
                z = __builtin_amdgcn_mfma_f32_32x32x16_bf16(kf, qf[step], z, 0, 0, 0);
            }
            __builtin_amdgcn_s_setprio(0);
#pragma unroll
            for (int g = 0; g < 4; ++g) {
                float4 bia = *(const float4*)&mbb[kt + kg * 32 + g * 8 + 4 * h];
                float p0 = __builtin_amdgcn_exp2f(fmaf(z[g * 4 + 0], SC, bia.x));
                float p1 = __builtin_amdgcn_exp2f(fmaf(z[g * 4 + 1], SC, bia.y));
                float p2 = __builtin_amdgcn_exp2f(fmaf(z[g * 4 + 2], SC, bia.z));
                float p3 = __builtin_amdgcn_exp2f(fmaf(z[g * 4 + 3], SC, bia.w));
                lsum += (p0 + p1) + (p2 + p3);
                bf16x8& pf = pa[kg * 2 + (g >> 1)];
                int jb = (g & 1) * 4;
                pf[jb + 0] = (bf16)p0;
                pf[jb + 1] = (bf16)p1;
                pf[jb + 2] = (bf16)p2;
                pf[jb + 3] = (bf16)p3;
            }
        }
        // O[q][d] += P V : A = P C-regs (key-permuted), B = permuted VpT frags
        __builtin_amdgcn_s_setprio(1);
#pragma unroll
        for (int t = 0; t < 2; ++t)
#pragma unroll
            for (int kk = 0; kk < 4; ++kk) {
                bf16x8 vf = *(const bf16x8*)&Vs[(t * 32 + l31) * 64 +
                                                (((kk * 2 + h) ^ x7) * 8)];
                o[t] = __builtin_amdgcn_mfma_f32_32x32x16_bf16(pa[kk], vf, o[t], 0, 0, 0);
            }
        __builtin_amdgcn_s_setprio(0);
    }

    // store partials (unnormalized O bf16 + lsum fp32)
    const size_t pbase = (size_t)(sp * 32 + bh) * 2048;
    {
        float ls = lsum + __shfl_xor(lsum, 32, 64);
        if (h == 0)
            Lpart[pbase + q0 + w * 32 + l31] = ls;
    }
#pragma unroll
    for (int t = 0; t < 2; ++t)
#pragma unroll
        for (int g = 0; g < 4; ++g)
#pragma unroll
            for (int rr = 0; rr < 4; ++rr) {
                int q = q0 + w * 32 + rr + g * 8 + 4 * h;
                Opart[(pbase + q) * 64 + t * 32 + l31] =
                    (bf16)o[t][g * 4 + rr];
            }
}

extern "C" void kernel_launch(void* const* d_in, const int* in_sizes, int n_in,
                              void* d_out, int out_size, void* d_ws, size_t ws_size,
                              hipStream_t stream) {
    const float* q   = (const float*)d_in[0];
    const float* kt  = (const float*)d_in[1];
    const float* v   = (const float*)d_in[2];
    const int* mask  = (const int*)d_in[3];
    const float* Wq  = (const float*)d_in[4];
    const float* bq  = (const float*)d_in[5];
    const float* Wk  = (const float*)d_in[6];
    const float* bk  = (const float*)d_in[7];
    const float* Wv  = (const float*)d_in[8];
    const float* bv  = (const float*)d_in[9];
    const float* Wo  = (const float*)d_in[10];
    const float* bo  = (const float*)d_in[11];
    float* out = (float*)d_out;

    char* ws = (char*)d_ws;
    const size_t SZ_IN = 4096ull * 1024 * 2;  // 8 MB bf16 activation
    const size_t SZ_W  = 1024ull * 1024 * 2;  // 2 MB bf16 weight
    bf16* qb  = (bf16*)(ws + 0 * SZ_IN);
    bf16* kb  = (bf16*)(ws + 1 * SZ_IN);
    bf16* vb  = (bf16*)(ws + 2 * SZ_IN);
    bf16* Wqb = (bf16*)(ws + 3 * SZ_IN);
    bf16* Wkb = (bf16*)(ws + 3 * SZ_IN + 1 * SZ_W);
    bf16* Wvb = (bf16*)(ws + 3 * SZ_IN + 2 * SZ_W);
    bf16* Wob = (bf16*)(ws + 3 * SZ_IN + 3 * SZ_W);
    bf16* Qp  = (bf16*)(ws + 3 * SZ_IN + 4 * SZ_W);
    bf16* Kp  = (bf16*)(ws + 4 * SZ_IN + 4 * SZ_W);
    bf16* VpT = (bf16*)(ws + 5 * SZ_IN + 4 * SZ_W);
    float* mb = (float*)(ws + 6 * SZ_IN + 4 * SZ_W);          // 16 KB (pad 1 MB)
    char*  p0 = ws + 6 * SZ_IN + 4 * SZ_W + (1 << 20);
    bf16* Opart = (bf16*)p0;                                   // 2*32*2048*64*2 = 16.8 MB
    float* Lpart = (float*)(p0 + 2ull * 32 * 2048 * 64 * 2);   // 0.5 MB

    const int NIN = 4096 * 1024, NW = 1024 * 1024;
    cast8_k<<<dim3(NIN / 2048, 1, 8), 256, 0, stream>>>(
        q, kt, v, Wq, Wk, Wv, Wo, qb, kb, vb, Wqb, Wkb, Wvb, Wob,
        mask, mb, NIN, NW);

    gemm_qkv<<<dim3(32, 8, 3), 256, 0, stream>>>(qb, kb, vb, Wqb, Wkb, Wvb,
                                                 bq, bk, bv, Qp, Kp, VpT);
    attn_k<<<dim3(1024), 256, 0, stream>>>(Qp, Kp, VpT, mb, Opart, Lpart);
    gemm_out_fused<<<dim3(512), 256, 0, stream>>>(Opart, Lpart, Wob, bo, out);
}

// Round 7
// 226.489 us; speedup vs baseline: 1.7555x; 1.0059x over previous
//
#include <hip/hip_runtime.h>
#include <hip/hip_bf16.h>

typedef __bf16 bf16;
typedef __bf16 bf16x8 __attribute__((ext_vector_type(8)));
typedef __bf16 bf16x4 __attribute__((ext_vector_type(4)));
typedef float  f32x4  __attribute__((ext_vector_type(4)));
typedef float  f32x16 __attribute__((ext_vector_type(16)));

#define AS1 __attribute__((address_space(1)))
#define AS3 __attribute__((address_space(3)))

__device__ __forceinline__ void gload_lds16(const bf16* g, bf16* l) {
    __builtin_amdgcn_global_load_lds((const AS1 unsigned int*)g,
                                     (AS3 unsigned int*)l, 16, 0, 0);
}

// ------- cast fp32 -> bf16 (7 tensors) + mask bias, via grid.z -------
__global__ __launch_bounds__(256) void cast8_k(
    const float* __restrict__ s0, const float* __restrict__ s1,
    const float* __restrict__ s2, const float* __restrict__ s3,
    const float* __restrict__ s4, const float* __restrict__ s5,
    const float* __restrict__ s6,
    bf16* __restrict__ d0, bf16* __restrict__ d1, bf16* __restrict__ d2,
    bf16* __restrict__ d3, bf16* __restrict__ d4, bf16* __restrict__ d5,
    bf16* __restrict__ d6,
    const int* __restrict__ m, float* __restrict__ mb,
    int n_big, int n_small) {
    int z = blockIdx.z;
    int i = (blockIdx.x * 256 + threadIdx.x) * 8;
    if (z == 7) {  // mask -> exp2-domain additive bias
        if (i >= 4096) return;
        int4 a = *(const int4*)(m + i);
        int4 b = *(const int4*)(m + i + 4);
        float4 o0, o1;
        o0.x = (a.x == 0) ? -1.442695e9f : -17.3123405f;
        o0.y = (a.y == 0) ? -1.442695e9f : -17.3123405f;
        o0.z = (a.z == 0) ? -1.442695e9f : -17.3123405f;
        o0.w = (a.w == 0) ? -1.442695e9f : -17.3123405f;
        o1.x = (b.x == 0) ? -1.442695e9f : -17.3123405f;
        o1.y = (b.y == 0) ? -1.442695e9f : -17.3123405f;
        o1.z = (b.z == 0) ? -1.442695e9f : -17.3123405f;
        o1.w = (b.w == 0) ? -1.442695e9f : -17.3123405f;
        *(float4*)(mb + i) = o0;
        *(float4*)(mb + i + 4) = o1;
        return;
    }
    const float* s = (z == 0) ? s0 : (z == 1) ? s1 : (z == 2) ? s2
                   : (z == 3) ? s3 : (z == 4) ? s4 : (z == 5) ? s5 : s6;
    bf16* d = (z == 0) ? d0 : (z == 1) ? d1 : (z == 2) ? d2
            : (z == 3) ? d3 : (z == 4) ? d4 : (z == 5) ? d5 : d6;
    int n = (z < 3) ? n_big : n_small;
    if (i >= n) return;
    float4 a = *(const float4*)(s + i);
    float4 b = *(const float4*)(s + i + 4);
    bf16x8 o;
    o[0] = (bf16)a.x; o[1] = (bf16)a.y; o[2] = (bf16)a.z; o[3] = (bf16)a.w;
    o[4] = (bf16)b.x; o[5] = (bf16)b.y; o[6] = (bf16)b.z; o[7] = (bf16)b.w;
    *(bf16x8*)(d + i) = o;
}

// ---------------- BT-GEMM, 32x32x16 MFMA, 128x128 tile ----------------
// TRANS=true: compute C^T and store to VpT with the bit2<->bit3 key
// permutation baked in (for attn's PV A-frag trick).
template <typename OUT_T, bool TRANS>
__device__ __forceinline__ void gemm32_core(
    const bf16* __restrict__ A, const bf16* __restrict__ W,
    const float* __restrict__ bias, OUT_T* __restrict__ C,
    int M, int N, int K) {
    __shared__ bf16 Asm[128 * 64];
    __shared__ bf16 Bsm[128 * 64];
    const int lane = threadIdx.x & 63;
    const int w = threadIdx.x >> 6;
    const int l31 = lane & 31;
    const int h = lane >> 5;
    const int x7 = l31 & 7;
    const int m0 = blockIdx.x * 128;
    const int n0 = blockIdx.y * 128;
    const int srow = lane >> 3;
    const int scol = ((lane & 7) ^ srow) * 8;
    const int wm = (w & 1) * 64;
    const int wn = (w >> 1) * 64;

    f32x16 acc[2][2] = {};

    for (int k0 = 0; k0 < K; k0 += 64) {
#pragma unroll
        for (int c = 0; c < 4; ++c) {
            int r = w * 32 + c * 8;
            gload_lds16(A + (size_t)(m0 + r + srow) * K + k0 + scol, &Asm[r * 64]);
            gload_lds16(W + (size_t)(n0 + r + srow) * K + k0 + scol, &Bsm[r * 64]);
        }
        __syncthreads();
#pragma unroll
        for (int step = 0; step < 4; ++step) {
            bf16x8 af[2], bfv[2];
#pragma unroll
            for (int i = 0; i < 2; ++i)
                af[i] = *(const bf16x8*)&Asm[(wm + i * 32 + l31) * 64 +
                                             (((step * 2 + h) ^ x7) * 8)];
#pragma unroll
            for (int j = 0; j < 2; ++j)
                bfv[j] = *(const bf16x8*)&Bsm[(wn + j * 32 + l31) * 64 +
                                              (((step * 2 + h) ^ x7) * 8)];
#pragma unroll
            for (int i = 0; i < 2; ++i)
#pragma unroll
                for (int j = 0; j < 2; ++j)
                    acc[i][j] = TRANS
                        ? __builtin_amdgcn_mfma_f32_32x32x16_bf16(bfv[j], af[i],
                                                                  acc[i][j], 0, 0, 0)
                        : __builtin_amdgcn_mfma_f32_32x32x16_bf16(af[i], bfv[j],
                                                                  acc[i][j], 0, 0, 0);
        }
        __syncthreads();
    }
    if (!TRANS) {
#pragma unroll
        for (int i = 0; i < 2; ++i)
#pragma unroll
            for (int j = 0; j < 2; ++j) {
                int col = n0 + wn + j * 32 + l31;
                float bv = bias[col];
#pragma unroll
                for (int g = 0; g < 4; ++g)
#pragma unroll
                    for (int rr = 0; rr < 4; ++rr) {
                        int row = m0 + wm + i * 32 + rr + g * 8 + 4 * h;
                        C[(size_t)row * N + col] =
                            (OUT_T)(acc[i][j][g * 4 + rr] + bv);
                    }
            }
    } else {
#pragma unroll
        for (int i = 0; i < 2; ++i) {
            int s = m0 + wm + i * 32 + l31;
            int b = s >> 11;
            int sl = s & 2047;
            int sp = (sl & ~12) | ((sl & 4) << 1) | ((sl & 8) >> 1);
#pragma unroll
            for (int j = 0; j < 2; ++j)
#pragma unroll
                for (int g = 0; g < 4; ++g) {
                    float4 bv4 = *(const float4*)&bias[n0 + wn + j * 32 + g * 8 + 4 * h];
#pragma unroll
                    for (int rr = 0; rr < 4; ++rr) {
                        int n = n0 + wn + j * 32 + g * 8 + 4 * h + rr;
                        C[(size_t)(b * 1024 + n) * 2048 + sp] =
                            (OUT_T)(acc[i][j][g * 4 + rr] + (&bv4.x)[rr]);
                    }
                }
        }
    }
}

__global__ __launch_bounds__(256) void gemm_qkv(
    const bf16* __restrict__ qb, const bf16* __restrict__ kb, const bf16* __restrict__ vb,
    const bf16* __restrict__ Wq, const bf16* __restrict__ Wk, const bf16* __restrict__ Wv,
    const float* __restrict__ bq, const float* __restrict__ bk, const float* __restrict__ bv,
    bf16* __restrict__ Qp, bf16* __restrict__ Kp, bf16* __restrict__ VpT) {
    int z = blockIdx.z;
    if (z == 2) {
        gemm32_core<bf16, true>(vb, Wv, bv, VpT, 4096, 1024, 1024);
    } else {
        const bf16* A = (z == 0) ? qb : kb;
        const bf16* W = (z == 0) ? Wq : Wk;
        const float* bi = (z == 0) ? bq : bk;
        bf16* C = (z == 0) ? Qp : Kp;
        gemm32_core<bf16, false>(A, W, bi, C, 4096, 1024, 1024);
    }
}

// ---- output GEMM with fused split-K combine in the A-staging ----
// 64x128 tile. A[row=token][col=dmodel] = (Op[sp0]+Op[sp1]) / (L0+L1),
// built on the fly and ds_written into the swizzled LDS layout.
// Grid 512 flat, swizzled: xt = id & 63 (same-A blocks share an XCD).
__global__ __launch_bounds__(256) void gemm_out_fused(
    const bf16* __restrict__ Op, const float* __restrict__ Lp,
    const bf16* __restrict__ W, const float* __restrict__ bias,
    float* __restrict__ C) {
    __shared__ bf16 Asm[64 * 64];
    __shared__ bf16 Bsm[128 * 64];
    const int id = blockIdx.x;
    const int m0 = (id & 63) * 64;
    const int n0 = (id >> 6) * 128;
    const int lane = threadIdx.x & 63;
    const int w = threadIdx.x >> 6;
    const int l31 = lane & 31;
    const int h = lane >> 5;
    const int x7 = l31 & 7;
    const int srow = lane >> 3;
    const int l7 = lane & 7;
    const int scol = (l7 ^ srow) * 8;
    const int wm = (w & 1) * 32;
    const int wn = (w >> 1) * 64;

    f32x16 acc[2] = {};

    for (int k0 = 0; k0 < 1024; k0 += 64) {
        // A staging: combine 2 split-K partials, normalize, swizzled ds_write
#pragma unroll
        for (int c = 0; c < 2; ++c) {
            int r = w * 16 + c * 8;
            int row = m0 + r + srow;             // token
            int colb = k0 + scol;                // dmodel col base (8-aligned)
            int b = row >> 11, q = row & 2047;
            int hh = colb >> 6, d = colb & 63;
            size_t l0i = (size_t)(b * 16 + hh) * 2048 + q;
            bf16x8 v0 = *(const bf16x8*)&Op[l0i * 64 + d];
            bf16x8 v1 = *(const bf16x8*)&Op[(l0i + 32 * 2048) * 64 + d];
            float inv = 1.0f / (Lp[l0i] + Lp[l0i + 32 * 2048]);
            bf16x8 o;
#pragma unroll
            for (int i = 0; i < 8; ++i)
                o[i] = (bf16)(((float)v0[i] + (float)v1[i]) * inv);
            *(bf16x8*)&Asm[(r + srow) * 64 + l7 * 8] = o;
        }
#pragma unroll
        for (int c = 0; c < 4; ++c) {
            int r = w * 32 + c * 8;
            gload_lds16(W + (size_t)(n0 + r + srow) * 1024 + k0 + scol, &Bsm[r * 64]);
        }
        __syncthreads();
#pragma unroll
        for (int step = 0; step < 4; ++step) {
            bf16x8 af = *(const bf16x8*)&Asm[(wm + l31) * 64 +
                                             (((step * 2 + h) ^ x7) * 8)];
            bf16x8 bfv[2];
#pragma unroll
            for (int j = 0; j < 2; ++j)
                bfv[j] = *(const bf16x8*)&Bsm[(wn + j * 32 + l31) * 64 +
                                              (((step * 2 + h) ^ x7) * 8)];
#pragma unroll
            for (int j = 0; j < 2; ++j)
                acc[j] = __builtin_amdgcn_mfma_f32_32x32x16_bf16(af, bfv[j],
                                                                 acc[j], 0, 0, 0);
        }
        __syncthreads();
    }
#pragma unroll
    for (int j = 0; j < 2; ++j) {
        int col = n0 + wn + j * 32 + l31;
        float bv = bias[col];
#pragma unroll
        for (int g = 0; g < 4; ++g)
#pragma unroll
            for (int rr = 0; rr < 4; ++rr) {
                int row = m0 + wm + rr + g * 8 + 4 * h;
                C[(size_t)row * 1024 + col] = acc[j][g * 4 + rr] + bv;
            }
    }
}

// ---------------- flash attention v9: round-0 body, 128-key barriers ----
// EXACT round-0 semantics (mb additive bias, fmaf+exp2 softmax, split-K=2,
// 64q/wave). Structural change only: each double-buffer slot holds TWO
// independent 64x64 sub-tiles (K0,K1,V0,V1); stage() fills both, and the
// unchanged 64-key body runs twice per barrier. Barriers 16 -> 8, each
// vmcnt(0) drain hides under 2x compute. LDS 64KB/block -> still
// 2 blocks/CU (128 <= 160 KB), VGPR unchanged.
__global__ __launch_bounds__(256, 2) void attn_k(
    const bf16* __restrict__ Qp, const bf16* __restrict__ Kp,
    const bf16* __restrict__ VpT, const float* __restrict__ mb,
    bf16* __restrict__ Opart, float* __restrict__ Lpart) {
    __shared__ bf16 KV[2][2][2][64 * 64];  // [buf][K|V][sub][.]
    const int g = blockIdx.x;
    const int qb = g >> 6;          // 0..7
    const int bh = (g & 63) >> 1;   // 0..31
    const int sp = g & 1;           // 0..1
    const int b = bh >> 4, hh = bh & 15;
    const int lane = threadIdx.x & 63, w = threadIdx.x >> 6;
    const int l31 = lane & 31, h = lane >> 5;
    const int x7 = l31 & 7;
    const int srow = lane >> 3, scol = ((lane & 7) ^ srow) * 8;
    const float SC = 0.125f * 1.44269504f;
    const int q0 = qb * 256;
    const int k0 = sp * 1024;

    const bf16* Kg = Kp + (size_t)(b * 2048) * 1024 + hh * 64;
    const bf16* Vg = VpT + (size_t)bh * 64 * 2048;
    const float* mbb = mb + b * 2048;

    auto stage = [&](int buf, int kt) {
#pragma unroll
        for (int sub = 0; sub < 2; ++sub)
#pragma unroll
            for (int c = 0; c < 2; ++c) {
                int r = w * 16 + c * 8;
                gload_lds16(Kg + (size_t)(kt + sub * 64 + r + srow) * 1024 + scol,
                            &KV[buf][0][sub][r * 64]);
                gload_lds16(Vg + (size_t)(r + srow) * 2048 + kt + sub * 64 + scol,
                            &KV[buf][1][sub][r * 64]);
            }
    };
    stage(0, k0);

    // Q B-frags for both 32-q groups: B[n=q][k=d]
    bf16x8 qf[2][4];
#pragma unroll
    for (int qg = 0; qg < 2; ++qg) {
        const bf16* Qbase =
            Qp + (size_t)(b * 2048 + q0 + w * 64 + qg * 32 + l31) * 1024 + hh * 64;
#pragma unroll
        for (int step = 0; step < 4; ++step)
            qf[qg][step] = *(const bf16x8*)(Qbase + step * 16 + h * 8);
    }

    f32x16 o[2][2] = {};  // [qg][d-group]
    float lsum[2] = {0.0f, 0.0f};

    for (int it = 0; it < 8; ++it) {
        __syncthreads();  // drains stage(it); prefetch below overlaps compute
        if (it < 7) stage((it + 1) & 1, k0 + (it + 1) * 128);
#pragma unroll
        for (int sub = 0; sub < 2; ++sub) {
            const bf16* Ks = KV[it & 1][0][sub];
            const bf16* Vs = KV[it & 1][1][sub];
            const int kt = k0 + it * 128 + sub * 64;

            bf16x8 pa[2][4];
#pragma unroll
            for (int kg = 0; kg < 2; ++kg) {
                f32x16 z0 = {}, z1 = {};
                __builtin_amdgcn_s_setprio(1);
#pragma unroll
                for (int step = 0; step < 4; ++step) {
                    bf16x8 kf = *(const bf16x8*)&Ks[(kg * 32 + l31) * 64 +
                                                    (((step * 2 + h) ^ x7) * 8)];
                    z0 = __builtin_amdgcn_mfma_f32_32x32x16_bf16(kf, qf[0][step], z0, 0, 0, 0);
                    z1 = __builtin_amdgcn_mfma_f32_32x32x16_bf16(kf, qf[1][step], z1, 0, 0, 0);
                }
                __builtin_amdgcn_s_setprio(0);
#pragma unroll
                for (int gg = 0; gg < 4; ++gg) {
                    float4 bia = *(const float4*)&mbb[kt + kg * 32 + gg * 8 + 4 * h];
#pragma unroll
                    for (int qg = 0; qg < 2; ++qg) {
                        const f32x16& z = qg ? z1 : z0;
                        float p0 = __builtin_amdgcn_exp2f(fmaf(z[gg * 4 + 0], SC, bia.x));
                        float p1 = __builtin_amdgcn_exp2f(fmaf(z[gg * 4 + 1], SC, bia.y));
                        float p2 = __builtin_amdgcn_exp2f(fmaf(z[gg * 4 + 2], SC, bia.z));
                        float p3 = __builtin_amdgcn_exp2f(fmaf(z[gg * 4 + 3], SC, bia.w));
                        lsum[qg] += (p0 + p1) + (p2 + p3);
                        bf16x8& pf = pa[qg][kg * 2 + (gg >> 1)];
                        int jb = (gg & 1) * 4;
                        pf[jb + 0] = (bf16)p0;
                        pf[jb + 1] = (bf16)p1;
                        pf[jb + 2] = (bf16)p2;
                        pf[jb + 3] = (bf16)p3;
                    }
                }
            }
            // O[q][d] += P V : A = P C-regs (key-permuted), B = permuted VpT frags
            __builtin_amdgcn_s_setprio(1);
#pragma unroll
            for (int t = 0; t < 2; ++t)
#pragma unroll
                for (int kk = 0; kk < 4; ++kk) {
                    bf16x8 vf = *(const bf16x8*)&Vs[(t * 32 + l31) * 64 +
                                                    (((kk * 2 + h) ^ x7) * 8)];
                    o[0][t] = __builtin_amdgcn_mfma_f32_32x32x16_bf16(pa[0][kk], vf, o[0][t], 0, 0, 0);
                    o[1][t] = __builtin_amdgcn_mfma_f32_32x32x16_bf16(pa[1][kk], vf, o[1][t], 0, 0, 0);
                }
            __builtin_amdgcn_s_setprio(0);
        }
    }

    // store partials (unnormalized O bf16 + lsum fp32)
    const size_t pbase = (size_t)(sp * 32 + bh) * 2048;
#pragma unroll
    for (int qg = 0; qg < 2; ++qg) {
        float ls = lsum[qg] + __shfl_xor(lsum[qg], 32, 64);
        if (h == 0)
            Lpart[pbase + q0 + w * 64 + qg * 32 + l31] = ls;
#pragma unroll
        for (int t = 0; t < 2; ++t)
#pragma unroll
            for (int gg = 0; gg < 4; ++gg)
#pragma unroll
                for (int rr = 0; rr < 4; ++rr) {
                    int q = q0 + w * 64 + qg * 32 + rr + gg * 8 + 4 * h;
                    Opart[(pbase + q) * 64 + t * 32 + l31] =
                        (bf16)o[qg][t][gg * 4 + rr];
                }
    }
}

extern "C" void kernel_launch(void* const* d_in, const int* in_sizes, int n_in,
                              void* d_out, int out_size, void* d_ws, size_t ws_size,
                              hipStream_t stream) {
    const float* q   = (const float*)d_in[0];
    const float* kt  = (const float*)d_in[1];
    const float* v   = (const float*)d_in[2];
    const int* mask  = (const int*)d_in[3];
    const float* Wq  = (const float*)d_in[4];
    const float* bq  = (const float*)d_in[5];
    const float* Wk  = (const float*)d_in[6];
    const float* bk  = (const float*)d_in[7];
    const float* Wv  = (const float*)d_in[8];
    const float* bv  = (const float*)d_in[9];
    const float* Wo  = (const float*)d_in[10];
    const float* bo  = (const float*)d_in[11];
    float* out = (float*)d_out;

    char* ws = (char*)d_ws;
    const size_t SZ_IN = 4096ull * 1024 * 2;  // 8 MB bf16 activation
    const size_t SZ_W  = 1024ull * 1024 * 2;  // 2 MB bf16 weight
    bf16* qb  = (bf16*)(ws + 0 * SZ_IN);
    bf16* kb  = (bf16*)(ws + 1 * SZ_IN);
    bf16* vb  = (bf16*)(ws + 2 * SZ_IN);
    bf16* Wqb = (bf16*)(ws + 3 * SZ_IN);
    bf16* Wkb = (bf16*)(ws + 3 * SZ_IN + 1 * SZ_W);
    bf16* Wvb = (bf16*)(ws + 3 * SZ_IN + 2 * SZ_W);
    bf16* Wob = (bf16*)(ws + 3 * SZ_IN + 3 * SZ_W);
    bf16* Qp  = (bf16*)(ws + 3 * SZ_IN + 4 * SZ_W);
    bf16* Kp  = (bf16*)(ws + 4 * SZ_IN + 4 * SZ_W);
    bf16* VpT = (bf16*)(ws + 5 * SZ_IN + 4 * SZ_W);
    float* mb = (float*)(ws + 6 * SZ_IN + 4 * SZ_W);          // 16 KB (pad 1 MB)
    char*  p0 = ws + 6 * SZ_IN + 4 * SZ_W + (1 << 20);
    bf16* Opart = (bf16*)p0;                                   // 2*32*2048*64*2 = 16.8 MB
    float* Lpart = (float*)(p0 + 2ull * 32 * 2048 * 64 * 2);   // 0.5 MB

    const int NIN = 4096 * 1024, NW = 1024 * 1024;
    cast8_k<<<dim3(NIN / 2048, 1, 8), 256, 0, stream>>>(
        q, kt, v, Wq, Wk, Wv, Wo, qb, kb, vb, Wqb, Wkb, Wvb, Wob,
        mask, mb, NIN, NW);

    gemm_qkv<<<dim3(32, 8, 3), 256, 0, stream>>>(qb, kb, vb, Wqb, Wkb, Wvb,
                                                 bq, bk, bv, Qp, Kp, VpT);
    attn_k<<<dim3(512), 256, 0, stream>>>(Qp, Kp, VpT, mb, Opart, Lpart);
    gemm_out_fused<<<dim3(512), 256, 0, stream>>>(Opart, Lpart, Wob, bo, out);
}